// Round 1
// baseline (294.755 us; speedup 1.0000x reference)
//
#include <hip/hip_runtime.h>
#include <stdint.h>

#define T_SEQ 4096
#define NB 2
#define D_MODEL 2048
#define HD 128

typedef __attribute__((ext_vector_type(4))) float f32x4;
typedef __attribute__((ext_vector_type(8))) short bf16x8;

#define LAMBDA_INIT 0.7836057665316244f
#define OUT_SCALE   0.21639423346837556f

__device__ __forceinline__ unsigned short f2bf(float f) {
  unsigned int u = __float_as_uint(f);
  u += 0x7FFFu + ((u >> 16) & 1u);
  return (unsigned short)(u >> 16);
}
__device__ __forceinline__ float bf2f(unsigned short h) {
  return __uint_as_float(((unsigned int)h) << 16);
}
__device__ __forceinline__ void gload16(const void* g, void* l) {
  __builtin_amdgcn_global_load_lds(
      (const __attribute__((address_space(1))) unsigned int*)g,
      (__attribute__((address_space(3))) unsigned int*)l, 16, 0, 0);
}

// ---------------- Kernel 1: QKV projection (hi/lo split-bf16 MFMA GEMM) ----
#define K1_LDP 40   // padded LDS stride (bf16 elems) -> 80B rows, 16B aligned, 2-way banks

__global__ __launch_bounds__(256) void qkv_proj(
    const float* __restrict__ x, const float* __restrict__ wq,
    const float* __restrict__ wk, const float* __restrict__ wv,
    unsigned short* __restrict__ qhi, unsigned short* __restrict__ qlo,
    unsigned short* __restrict__ khi, unsigned short* __restrict__ klo,
    unsigned short* __restrict__ vt)
{
  __shared__ __align__(16) unsigned short Ah[128 * K1_LDP], Al[128 * K1_LDP];
  __shared__ __align__(16) unsigned short Bh[128 * K1_LDP], Bl[128 * K1_LDP];
  const int which = blockIdx.y;                 // 0=q,1=k,2=v
  const float* w = (which == 0) ? wq : ((which == 1) ? wk : wv);
  const int m0 = blockIdx.x * 128;
  const int tid = threadIdx.x;
  const int lane = tid & 63, wid = tid >> 6;
  const int wm = wid >> 1, wn = wid & 1;        // 2x2 waves of 64x64
  const int fr = lane & 15, fq = lane >> 4;
  const int fk = fq << 3;

  f32x4 acc[4][4];
  #pragma unroll
  for (int i = 0; i < 4; ++i)
    #pragma unroll
    for (int j = 0; j < 4; ++j) acc[i][j] = (f32x4){0.f, 0.f, 0.f, 0.f};

  for (int k0 = 0; k0 < D_MODEL; k0 += 32) {
    __syncthreads();
    // stage x tile: 128 rows x 32 cols (f32 -> hi/lo bf16)
    #pragma unroll
    for (int c = 0; c < 4; ++c) {
      int id = tid + c * 256;
      int r = id >> 3, c4 = (id & 7) << 2;
      f32x4 xv = *reinterpret_cast<const f32x4*>(&x[(size_t)(m0 + r) * D_MODEL + k0 + c4]);
      uint2 ph, pl;
      unsigned short h0 = f2bf(xv[0]), h1 = f2bf(xv[1]), h2 = f2bf(xv[2]), h3 = f2bf(xv[3]);
      unsigned short l0 = f2bf(xv[0] - bf2f(h0)), l1 = f2bf(xv[1] - bf2f(h1));
      unsigned short l2 = f2bf(xv[2] - bf2f(h2)), l3 = f2bf(xv[3] - bf2f(h3));
      ph.x = (unsigned)h0 | ((unsigned)h1 << 16); ph.y = (unsigned)h2 | ((unsigned)h3 << 16);
      pl.x = (unsigned)l0 | ((unsigned)l1 << 16); pl.y = (unsigned)l2 | ((unsigned)l3 << 16);
      *reinterpret_cast<uint2*>(&Ah[r * K1_LDP + c4]) = ph;
      *reinterpret_cast<uint2*>(&Al[r * K1_LDP + c4]) = pl;
    }
    // stage w tile 32k x 128n, transposed into [n][k]
    #pragma unroll
    for (int c = 0; c < 4; ++c) {
      int id = tid + c * 256;
      int n = id & 127, kc = (id >> 7) << 2;
      float w0 = w[(size_t)(k0 + kc + 0) * HD + n];
      float w1 = w[(size_t)(k0 + kc + 1) * HD + n];
      float w2 = w[(size_t)(k0 + kc + 2) * HD + n];
      float w3 = w[(size_t)(k0 + kc + 3) * HD + n];
      unsigned short h0 = f2bf(w0), h1 = f2bf(w1), h2 = f2bf(w2), h3 = f2bf(w3);
      unsigned short l0 = f2bf(w0 - bf2f(h0)), l1 = f2bf(w1 - bf2f(h1));
      unsigned short l2 = f2bf(w2 - bf2f(h2)), l3 = f2bf(w3 - bf2f(h3));
      uint2 ph, pl;
      ph.x = (unsigned)h0 | ((unsigned)h1 << 16); ph.y = (unsigned)h2 | ((unsigned)h3 << 16);
      pl.x = (unsigned)l0 | ((unsigned)l1 << 16); pl.y = (unsigned)l2 | ((unsigned)l3 << 16);
      *reinterpret_cast<uint2*>(&Bh[n * K1_LDP + kc]) = ph;
      *reinterpret_cast<uint2*>(&Bl[n * K1_LDP + kc]) = pl;
    }
    __syncthreads();
    bf16x8 ah[4], al[4], bh[4], bl[4];
    #pragma unroll
    for (int mi = 0; mi < 4; ++mi) {
      int row = wm * 64 + mi * 16 + fr;
      ah[mi] = *reinterpret_cast<bf16x8*>(&Ah[row * K1_LDP + fk]);
      al[mi] = *reinterpret_cast<bf16x8*>(&Al[row * K1_LDP + fk]);
    }
    #pragma unroll
    for (int ni = 0; ni < 4; ++ni) {
      int row = wn * 64 + ni * 16 + fr;
      bh[ni] = *reinterpret_cast<bf16x8*>(&Bh[row * K1_LDP + fk]);
      bl[ni] = *reinterpret_cast<bf16x8*>(&Bl[row * K1_LDP + fk]);
    }
    #pragma unroll
    for (int mi = 0; mi < 4; ++mi)
      #pragma unroll
      for (int ni = 0; ni < 4; ++ni) {
        acc[mi][ni] = __builtin_amdgcn_mfma_f32_16x16x32_bf16(ah[mi], bh[ni], acc[mi][ni], 0, 0, 0);
        acc[mi][ni] = __builtin_amdgcn_mfma_f32_16x16x32_bf16(ah[mi], bl[ni], acc[mi][ni], 0, 0, 0);
        acc[mi][ni] = __builtin_amdgcn_mfma_f32_16x16x32_bf16(al[mi], bh[ni], acc[mi][ni], 0, 0, 0);
      }
  }
  // epilogue: D[m=(fq*4+r)][n=fr] per 16x16 frag
  #pragma unroll
  for (int mi = 0; mi < 4; ++mi)
    #pragma unroll
    for (int ni = 0; ni < 4; ++ni) {
      int n = wn * 64 + ni * 16 + fr;
      #pragma unroll
      for (int r = 0; r < 4; ++r) {
        int m = m0 + wm * 64 + mi * 16 + fq * 4 + r;
        float vv = acc[mi][ni][r];
        if (which == 2) {
          int bb = m >> 12, t = m & 4095;
          vt[((size_t)bb * HD + n) * T_SEQ + t] = f2bf(vv);
        } else {
          unsigned short h = f2bf(vv);
          unsigned short l = f2bf(vv - bf2f(h));
          size_t idx = (size_t)m * HD + n;
          if (which == 0) { qhi[idx] = h; qlo[idx] = l; }
          else            { khi[idx] = h; klo[idx] = l; }
        }
      }
    }
}

// ---------------- Kernel 2: diff flash attention --------------------------
// grid (128, 2): block handles q-tile pair (i, 255-i) of batch blockIdx.y.
// QBLK=16 rows, KVBLK=64. 4 waves; wave w owns kv cols [16w,16w+16) for QK
// and v cols [32w,32w+32) for PV.
__global__ __launch_bounds__(256) void diff_attn(
    const unsigned short* __restrict__ qhi, const unsigned short* __restrict__ qlo,
    const unsigned short* __restrict__ khi, const unsigned short* __restrict__ klo,
    const unsigned short* __restrict__ vt,
    const float* __restrict__ lq1, const float* __restrict__ lq2,
    const float* __restrict__ lk1, const float* __restrict__ lk2,
    const float* __restrict__ lnw, float* __restrict__ out)
{
  __shared__ __align__(16) unsigned short Khi[64 * 128];   // swizzled, rows 256B
  __shared__ __align__(16) unsigned short Klo[64 * 128];
  __shared__ __align__(16) unsigned short Vt[128 * 64];    // [vc][kv], swizzled, rows 128B
  __shared__ __align__(16) unsigned short P1[16 * 72], P2[16 * 72];
  __shared__ __align__(16) float Mbuf[2][16][4];
  __shared__ __align__(16) float Sbuf[2][16][4];

  const int tid = threadIdx.x, lane = tid & 63, wid = tid >> 6;
  const int batch = blockIdx.y;
  const int fr = lane & 15, fq = lane >> 4;
  const int kvcol = wid * 16 + fr;

  // lambda (all waves compute identically; h=64 == wave size)
  float la = lq1[lane] * lk1[lane];
  float lb = lq2[lane] * lk2[lane];
  #pragma unroll
  for (int off = 32; off >= 1; off >>= 1) {
    la += __shfl_xor(la, off);
    lb += __shfl_xor(lb, off);
  }
  const float lam = __expf(la) - __expf(lb) + LAMBDA_INIT;

  const float lnw0 = lnw[wid * 32 + fr];
  const float lnw1 = lnw[wid * 32 + 16 + fr];

  for (int tix = 0; tix < 2; ++tix) {
    const int qt = tix ? (255 - (int)blockIdx.x) : (int)blockIdx.x;
    const int q0 = qt * 16;
    // q fragments (hi/lo), A-layout: row=fr, k=fq*8+e
    bf16x8 qfh[2][2], qfl[2][2];
    {
      size_t base = ((size_t)batch * T_SEQ + q0 + fr) * HD;
      #pragma unroll
      for (int h = 0; h < 2; ++h)
        #pragma unroll
        for (int s = 0; s < 2; ++s) {
          size_t off = base + h * 64 + s * 32 + fq * 8;
          qfh[h][s] = *reinterpret_cast<const bf16x8*>(&qhi[off]);
          qfl[h][s] = *reinterpret_cast<const bf16x8*>(&qlo[off]);
        }
    }
    float mrun[2][4], lrun[2][4];
    f32x4 oacc[2][2];
    #pragma unroll
    for (int h = 0; h < 2; ++h) {
      #pragma unroll
      for (int r = 0; r < 4; ++r) { mrun[h][r] = -1e30f; lrun[h][r] = 0.f; }
      oacc[h][0] = (f32x4){0.f, 0.f, 0.f, 0.f};
      oacc[h][1] = (f32x4){0.f, 0.f, 0.f, 0.f};
    }
    const int nt = (q0 + 16 + 63) >> 6;
    for (int kt = 0; kt < nt; ++kt) {
      const int kv0 = kt * 64;
      __syncthreads();   // prev iteration done reading LDS
      // stage K hi/lo (16KB each) + Vt (16KB) via global_load_lds,
      // linear LDS dest + inverse-swizzled global source (XOR (row&7)<<4)
      #pragma unroll
      for (int c = 0; c < 4; ++c) {
        int cb = (wid * 4 + c) * 1024;        // wave-uniform chunk base
        int o = cb + lane * 16;
        int so = o ^ (((o >> 8) & 7) << 4);
        int row = so >> 8, col = (so & 255) >> 1;
        size_t g = ((size_t)batch * T_SEQ + kv0 + row) * HD + col;
        gload16(&khi[g], (char*)Khi + cb);
        gload16(&klo[g], (char*)Klo + cb);
        int so2 = o ^ (((o >> 7) & 7) << 4);
        int row2 = so2 >> 7, col2 = (so2 & 127) >> 1;
        size_t g2 = ((size_t)batch * HD + row2) * T_SEQ + kv0 + col2;
        gload16(&vt[g2], (char*)Vt + cb);
      }
      __syncthreads();   // staging complete
      // QK^T (hi*hi + hi*lo + lo*hi)
      f32x4 sc[2];
      sc[0] = (f32x4){0.f, 0.f, 0.f, 0.f};
      sc[1] = (f32x4){0.f, 0.f, 0.f, 0.f};
      #pragma unroll
      for (int h = 0; h < 2; ++h)
        #pragma unroll
        for (int s = 0; s < 2; ++s) {
          int by = kvcol * 256 + (h * 64 + s * 32 + fq * 8) * 2;
          by ^= ((kvcol & 7) << 4);
          bf16x8 kh = *reinterpret_cast<bf16x8*>((char*)Khi + by);
          bf16x8 kl = *reinterpret_cast<bf16x8*>((char*)Klo + by);
          sc[h] = __builtin_amdgcn_mfma_f32_16x16x32_bf16(qfh[h][s], kh, sc[h], 0, 0, 0);
          sc[h] = __builtin_amdgcn_mfma_f32_16x16x32_bf16(qfh[h][s], kl, sc[h], 0, 0, 0);
          sc[h] = __builtin_amdgcn_mfma_f32_16x16x32_bf16(qfl[h][s], kh, sc[h], 0, 0, 0);
        }
      // scale + causal mask (col > row masked)
      const int kvg = kv0 + kvcol;
      #pragma unroll
      for (int h = 0; h < 2; ++h)
        #pragma unroll
        for (int r = 0; r < 4; ++r) {
          float sv = sc[h][r] * 0.125f;
          if (kvg > q0 + fq * 4 + r) sv = -1e30f;
          sc[h][r] = sv;
        }
      // tile row max: intra-wave over fr, cross-wave via Mbuf
      float tmax[2][4];
      #pragma unroll
      for (int h = 0; h < 2; ++h)
        #pragma unroll
        for (int r = 0; r < 4; ++r) {
          float v = sc[h][r];
          #pragma unroll
          for (int off = 8; off >= 1; off >>= 1) v = fmaxf(v, __shfl_xor(v, off));
          tmax[h][r] = v;
        }
      if (fr == 0) {
        #pragma unroll
        for (int h = 0; h < 2; ++h)
          #pragma unroll
          for (int r = 0; r < 4; ++r) Mbuf[h][fq * 4 + r][wid] = tmax[h][r];
      }
      __syncthreads();
      float alpha[2][4];
      float psum[2][4];
      #pragma unroll
      for (int h = 0; h < 2; ++h)
        #pragma unroll
        for (int r = 0; r < 4; ++r) {
          f32x4 m4 = *reinterpret_cast<f32x4*>(&Mbuf[h][fq * 4 + r][0]);
          float mt = fmaxf(fmaxf(m4[0], m4[1]), fmaxf(m4[2], m4[3]));
          float mo = mrun[h][r];
          float mn = fmaxf(mo, mt);
          mrun[h][r] = mn;
          alpha[h][r] = __expf(mo - mn);
          float p = __expf(sc[h][r] - mn);
          sc[h][r] = p;
          float v = p;
          #pragma unroll
          for (int off = 8; off >= 1; off >>= 1) v += __shfl_xor(v, off);
          psum[h][r] = v;
        }
      // write P (bf16) + partial sums
      #pragma unroll
      for (int r = 0; r < 4; ++r) {
        P1[(fq * 4 + r) * 72 + wid * 16 + fr] = f2bf(sc[0][r]);
        P2[(fq * 4 + r) * 72 + wid * 16 + fr] = f2bf(sc[1][r]);
      }
      if (fr == 0) {
        #pragma unroll
        for (int h = 0; h < 2; ++h)
          #pragma unroll
          for (int r = 0; r < 4; ++r) Sbuf[h][fq * 4 + r][wid] = psum[h][r];
      }
      __syncthreads();
      // l update + o rescale
      #pragma unroll
      for (int h = 0; h < 2; ++h)
        #pragma unroll
        for (int r = 0; r < 4; ++r) {
          f32x4 s4 = *reinterpret_cast<f32x4*>(&Sbuf[h][fq * 4 + r][0]);
          float ts = s4[0] + s4[1] + s4[2] + s4[3];
          lrun[h][r] = alpha[h][r] * lrun[h][r] + ts;
          oacc[h][0][r] *= alpha[h][r];
          oacc[h][1][r] *= alpha[h][r];
        }
      // PV: A = P[row=fr][kv=s*32+fq*8+e], B = Vt[vc][kv]
      #pragma unroll
      for (int s = 0; s < 2; ++s) {
        bf16x8 pf1 = *reinterpret_cast<bf16x8*>(&P1[fr * 72 + s * 32 + fq * 8]);
        bf16x8 pf2 = *reinterpret_cast<bf16x8*>(&P2[fr * 72 + s * 32 + fq * 8]);
        #pragma unroll
        for (int ni = 0; ni < 2; ++ni) {
          int vc = wid * 32 + ni * 16 + fr;
          int by = vc * 128 + (s * 32 + fq * 8) * 2;
          by ^= ((vc & 7) << 4);
          bf16x8 vf = *reinterpret_cast<bf16x8*>((char*)Vt + by);
          oacc[0][ni] = __builtin_amdgcn_mfma_f32_16x16x32_bf16(pf1, vf, oacc[0][ni], 0, 0, 0);
          oacc[1][ni] = __builtin_amdgcn_mfma_f32_16x16x32_bf16(pf2, vf, oacc[1][ni], 0, 0, 0);
        }
      }
    } // kv loop
    // epilogue: d = o1/l1 - lam*o2/l2, RMS over 128 cols, scale, store
    __syncthreads();
    float dd[2][4];
    #pragma unroll
    for (int r = 0; r < 4; ++r) {
      float i1 = 1.f / lrun[0][r];
      float i2 = lam / lrun[1][r];
      dd[0][r] = oacc[0][0][r] * i1 - oacc[1][0][r] * i2;
      dd[1][r] = oacc[0][1][r] * i1 - oacc[1][1][r] * i2;
      float ss = dd[0][r] * dd[0][r] + dd[1][r] * dd[1][r];
      #pragma unroll
      for (int off = 8; off >= 1; off >>= 1) ss += __shfl_xor(ss, off);
      if (fr == 0) Sbuf[0][fq * 4 + r][wid] = ss;
    }
    __syncthreads();
    #pragma unroll
    for (int r = 0; r < 4; ++r) {
      f32x4 s4 = *reinterpret_cast<f32x4*>(&Sbuf[0][fq * 4 + r][0]);
      float tot = s4[0] + s4[1] + s4[2] + s4[3];
      float rinv = 1.f / sqrtf(tot * (1.0f / HD) + 1e-5f);
      int row = q0 + fq * 4 + r;
      size_t ob = ((size_t)batch * T_SEQ + row) * HD + wid * 32 + fr;
      out[ob]      = OUT_SCALE * dd[0][r] * rinv * lnw0;
      out[ob + 16] = OUT_SCALE * dd[1][r] * rinv * lnw1;
    }
  } // q-tile pair loop
}

extern "C" void kernel_launch(void* const* d_in, const int* in_sizes, int n_in,
                              void* d_out, int out_size, void* d_ws, size_t ws_size,
                              hipStream_t stream) {
  const float* x   = (const float*)d_in[0];
  const float* wq  = (const float*)d_in[1];
  const float* wk  = (const float*)d_in[2];
  const float* wv  = (const float*)d_in[3];
  const float* lq1 = (const float*)d_in[4];
  const float* lq2 = (const float*)d_in[5];
  const float* lk1 = (const float*)d_in[6];
  const float* lk2 = (const float*)d_in[7];
  const float* lnw = (const float*)d_in[8];
  float* out = (float*)d_out;

  const size_t N = (size_t)NB * T_SEQ * HD;   // 1,048,576 elems
  unsigned short* qhi = (unsigned short*)d_ws;
  unsigned short* qlo = qhi + N;
  unsigned short* khi = qlo + N;
  unsigned short* klo = khi + N;
  unsigned short* vt  = klo + N;              // total 10 MiB of ws

  qkv_proj<<<dim3(64, 3), 256, 0, stream>>>(x, wq, wk, wv, qhi, qlo, khi, klo, vt);
  diff_attn<<<dim3(128, 2), 256, 0, stream>>>(qhi, qlo, khi, klo, vt,
                                              lq1, lq2, lk1, lk2, lnw, out);
}

// Round 4
// 154.100 us; speedup vs baseline: 1.9128x; 1.9128x over previous
//
#include <hip/hip_runtime.h>
#include <stdint.h>

#define T_SEQ 4096
#define NB 2
#define D_MODEL 2048
#define HD 128

typedef __attribute__((ext_vector_type(4)))  float f32x4;
typedef __attribute__((ext_vector_type(16))) float f32x16;
typedef __attribute__((ext_vector_type(8)))  short bf16x8;
typedef __attribute__((ext_vector_type(4)))  unsigned u32x4;

#define LAMBDA_INIT 0.7836057665316244f
#define OUT_SCALE   0.21639423346837556f

__device__ __forceinline__ unsigned short f2bf(float f) {
  unsigned int u = __float_as_uint(f);
  u += 0x7FFFu + ((u >> 16) & 1u);
  return (unsigned short)(u >> 16);
}
__device__ __forceinline__ float bf2f(unsigned short h) {
  return __uint_as_float(((unsigned int)h) << 16);
}
__device__ __forceinline__ unsigned cvt_pk_bf16(float a, float b) {
  unsigned r;
  asm("v_cvt_pk_bf16_f32 %0, %1, %2" : "=v"(r) : "v"(a), "v"(b));
  return r;
}

// ---------------- Kernel 1: QKV projection (bf16 MFMA GEMM) ---------------
// M-tile 64, N=128. grid (128, 3). q gets SCALE=0.125 folded in (exact).
#define K1_LDP 40

__global__ __launch_bounds__(256) void qkv_proj(
    const float* __restrict__ x, const float* __restrict__ wq,
    const float* __restrict__ wk, const float* __restrict__ wv,
    unsigned short* __restrict__ qb, unsigned short* __restrict__ kb,
    unsigned short* __restrict__ vt)
{
  __shared__ __align__(16) unsigned short Ah[64 * K1_LDP];
  __shared__ __align__(16) unsigned short Bh[128 * K1_LDP];
  const int which = blockIdx.y;                 // 0=q,1=k,2=v
  const float* w = (which == 0) ? wq : ((which == 1) ? wk : wv);
  const int m0 = blockIdx.x * 64;
  const int tid = threadIdx.x;
  const int lane = tid & 63, wid = tid >> 6;
  const int wm = wid >> 1, wn = wid & 1;        // wave tile 32(m) x 64(n)
  const int fr = lane & 15, fq = lane >> 4;
  const int fk = fq << 3;

  f32x4 acc[2][4];
  #pragma unroll
  for (int i = 0; i < 2; ++i)
    #pragma unroll
    for (int j = 0; j < 4; ++j) acc[i][j] = (f32x4){0.f, 0.f, 0.f, 0.f};

  f32x4 arg[2], brg[4];
  #pragma unroll
  for (int c = 0; c < 2; ++c) {
    int id = tid + c * 256, r = id >> 3, c4 = (id & 7) << 2;
    arg[c] = *reinterpret_cast<const f32x4*>(&x[(size_t)(m0 + r) * D_MODEL + c4]);
  }
  #pragma unroll
  for (int c = 0; c < 4; ++c) {
    int id = tid + c * 256, n = id & 127, kc = (id >> 7) << 2;
    #pragma unroll
    for (int j = 0; j < 4; ++j) brg[c][j] = w[(size_t)(kc + j) * HD + n];
  }

  for (int it = 0; it < 64; ++it) {
    #pragma unroll
    for (int c = 0; c < 2; ++c) {
      int id = tid + c * 256, r = id >> 3, c4 = (id & 7) << 2;
      uint2 ph;
      ph.x = cvt_pk_bf16(arg[c][0], arg[c][1]);
      ph.y = cvt_pk_bf16(arg[c][2], arg[c][3]);
      *reinterpret_cast<uint2*>(&Ah[r * K1_LDP + c4]) = ph;
    }
    #pragma unroll
    for (int c = 0; c < 4; ++c) {
      int id = tid + c * 256, n = id & 127, kc = (id >> 7) << 2;
      uint2 ph;
      ph.x = cvt_pk_bf16(brg[c][0], brg[c][1]);
      ph.y = cvt_pk_bf16(brg[c][2], brg[c][3]);
      *reinterpret_cast<uint2*>(&Bh[n * K1_LDP + kc]) = ph;
    }
    __syncthreads();
    if (it < 63) {
      int k0n = (it + 1) * 32;
      #pragma unroll
      for (int c = 0; c < 2; ++c) {
        int id = tid + c * 256, r = id >> 3, c4 = (id & 7) << 2;
        arg[c] = *reinterpret_cast<const f32x4*>(&x[(size_t)(m0 + r) * D_MODEL + k0n + c4]);
      }
      #pragma unroll
      for (int c = 0; c < 4; ++c) {
        int id = tid + c * 256, n = id & 127, kc = (id >> 7) << 2;
        #pragma unroll
        for (int j = 0; j < 4; ++j) brg[c][j] = w[(size_t)(k0n + kc + j) * HD + n];
      }
    }
    bf16x8 ah[2], bh[4];
    #pragma unroll
    for (int mi = 0; mi < 2; ++mi)
      ah[mi] = *reinterpret_cast<bf16x8*>(&Ah[(wm * 32 + mi * 16 + fr) * K1_LDP + fk]);
    #pragma unroll
    for (int ni = 0; ni < 4; ++ni)
      bh[ni] = *reinterpret_cast<bf16x8*>(&Bh[(wn * 64 + ni * 16 + fr) * K1_LDP + fk]);
    #pragma unroll
    for (int mi = 0; mi < 2; ++mi)
      #pragma unroll
      for (int ni = 0; ni < 4; ++ni)
        acc[mi][ni] = __builtin_amdgcn_mfma_f32_16x16x32_bf16(ah[mi], bh[ni], acc[mi][ni], 0, 0, 0);
    __syncthreads();
  }
  #pragma unroll
  for (int mi = 0; mi < 2; ++mi)
    #pragma unroll
    for (int ni = 0; ni < 4; ++ni) {
      int n = wn * 64 + ni * 16 + fr;
      #pragma unroll
      for (int r = 0; r < 4; ++r) {
        int m = m0 + wm * 32 + mi * 16 + fq * 4 + r;
        float vv = acc[mi][ni][r];
        if (which == 2) {
          int bb = m >> 12, t = m & 4095;
          vt[((size_t)bb * HD + n) * T_SEQ + t] = f2bf(vv);
        } else if (which == 0) {
          qb[(size_t)m * HD + n] = f2bf(vv * 0.125f);   // fold softmax scale
        } else {
          kb[(size_t)m * HD + n] = f2bf(vv);
        }
      }
    }
}

// ---------------- Kernel 2: per-wave flash partials -----------------------
// wave_id = ((b*128 + qt)*2 + g)*S + sp. Wave: 32 q-rows, one score group,
// kv-split sp of S. Swapped QK (mfma(K,Q)): lane owns q-col = lane&31.
// No LDS, no syncthreads.
template<int LOG2S>
__global__ __launch_bounds__(256, 2) void diff_attn_part(
    const unsigned short* __restrict__ qb, const unsigned short* __restrict__ kb,
    const unsigned short* __restrict__ vt,
    unsigned short* __restrict__ po, float* __restrict__ pm, float* __restrict__ pl)
{
  constexpr int S = 1 << LOG2S;
  const int tid = threadIdx.x, lane = tid & 63, wid = tid >> 6;
  const int wave_id = blockIdx.x * 4 + wid;
  const int sp = wave_id & (S - 1);
  const int g  = (wave_id >> LOG2S) & 1;
  const int qt = (wave_id >> (LOG2S + 1)) & 127;
  const int b  = wave_id >> (LOG2S + 8);
  const int lq = lane & 31, lh = lane >> 5;
  const int q0 = qt * 32;
  const int n  = qt + 1;
  const int kt0 = (n * sp) >> LOG2S;
  const int kt1 = (n * (sp + 1)) >> LOG2S;

  // Q as B-operand: col=q=lq, k = ks*16 + lh*8 + e
  bf16x8 qf[4];
  const unsigned short* qp = qb + ((size_t)b * T_SEQ + q0 + lq) * HD + g * 64 + lh * 8;
  #pragma unroll
  for (int ks = 0; ks < 4; ++ks) qf[ks] = *reinterpret_cast<const bf16x8*>(qp + ks * 16);

  f32x16 acc[4];
  #pragma unroll
  for (int v = 0; v < 4; ++v)
    #pragma unroll
    for (int r = 0; r < 16; ++r) acc[v][r] = 0.f;
  float mrun = -1e30f, lrun = 0.f;

  const unsigned short* kp = kb + ((size_t)b * T_SEQ + lq) * HD + g * 64 + lh * 8;
  const unsigned short* vp = vt + ((size_t)b * HD + lq) * T_SEQ + lh * 8;

  for (int kt = kt0; kt < kt1; ++kt) {
    const int kv0 = kt * 32;
    bf16x8 kf[4];
    #pragma unroll
    for (int ks = 0; ks < 4; ++ks)
      kf[ks] = *reinterpret_cast<const bf16x8*>(kp + (size_t)kv0 * HD + ks * 16);
    f32x16 sc;
    #pragma unroll
    for (int r = 0; r < 16; ++r) sc[r] = 0.f;
    #pragma unroll
    for (int ks = 0; ks < 4; ++ks)
      sc = __builtin_amdgcn_mfma_f32_32x32x16_bf16(kf[ks], qf[ks], sc, 0, 0, 0);

    float p[16];
    if (kt == n - 1) {      // diagonal tile: mask kv_local > q_local
      #pragma unroll
      for (int r = 0; r < 16; ++r) {
        int rloc = (r & 3) + 8 * (r >> 2) + 4 * lh;
        p[r] = (rloc > lq) ? -1e30f : sc[r];
      }
    } else {
      #pragma unroll
      for (int r = 0; r < 16; ++r) p[r] = sc[r];
    }
    // column max over 32 rows (16 local + partner half)
    float t16[16];
    #pragma unroll
    for (int r = 0; r < 16; ++r) t16[r] = p[r];
    #pragma unroll
    for (int st = 8; st >= 1; st >>= 1)
      #pragma unroll
      for (int r = 0; r < 8; ++r)
        if (r < st) t16[r] = fmaxf(t16[r], t16[r + st]);
    float pmax = fmaxf(t16[0], __shfl_xor(t16[0], 32));
    if (__any(pmax > mrun + 8.f)) {          // T13 defer-max
      float mn = fmaxf(mrun, pmax);
      float al = __expf(mrun - mn);
      lrun *= al;
      #pragma unroll
      for (int v = 0; v < 4; ++v)
        #pragma unroll
        for (int r = 0; r < 16; ++r) acc[v][r] *= al;
      mrun = mn;
    }
    float psum;
    {
      float s16[16];
      #pragma unroll
      for (int r = 0; r < 16; ++r) { p[r] = __expf(p[r] - mrun); s16[r] = p[r]; }
      #pragma unroll
      for (int st = 8; st >= 1; st >>= 1)
        #pragma unroll
        for (int r = 0; r < 8; ++r)
          if (r < st) s16[r] += s16[r + st];
      psum = s16[0];
    }
    lrun += psum + __shfl_xor(psum, 32);     // full column sum (local + partner)

    // pack P -> B-frags via partner exchange (shfl_xor 32, known semantics).
    // lane (lh) holds P rows rloc = (r&3)+8*(r>>2)+4*lh for its q-column.
    // pb0 needs e0..7 = kv (lh?8:0)..(lh?15:7); pb1 same +16.
    unsigned A0 = cvt_pk_bf16(p[0],  p[1]),  A1 = cvt_pk_bf16(p[2],  p[3]);
    unsigned A2 = cvt_pk_bf16(p[4],  p[5]),  A3 = cvt_pk_bf16(p[6],  p[7]);
    unsigned A4 = cvt_pk_bf16(p[8],  p[9]),  A5 = cvt_pk_bf16(p[10], p[11]);
    unsigned A6 = cvt_pk_bf16(p[12], p[13]), A7 = cvt_pk_bf16(p[14], p[15]);
    unsigned pA0 = (unsigned)__shfl_xor((int)A0, 32);
    unsigned pA1 = (unsigned)__shfl_xor((int)A1, 32);
    unsigned pA2 = (unsigned)__shfl_xor((int)A2, 32);
    unsigned pA3 = (unsigned)__shfl_xor((int)A3, 32);
    unsigned pA4 = (unsigned)__shfl_xor((int)A4, 32);
    unsigned pA5 = (unsigned)__shfl_xor((int)A5, 32);
    unsigned pA6 = (unsigned)__shfl_xor((int)A6, 32);
    unsigned pA7 = (unsigned)__shfl_xor((int)A7, 32);
    // lh=0: w0={A0,A1,pA0,pA1} (rows 0-3 | partner rows 4-7)
    // lh=1: w0={pA2,pA3,A2,A3} (partner rows 8-11 | rows 12-15)
    u32x4 w0, w1;
    w0[0] = lh ? pA2 : A0;  w0[1] = lh ? pA3 : A1;
    w0[2] = lh ? A2  : pA0; w0[3] = lh ? A3  : pA1;
    w1[0] = lh ? pA6 : A4;  w1[1] = lh ? pA7 : A5;
    w1[2] = lh ? A6  : pA4; w1[3] = lh ? A7  : pA5;
    bf16x8 pb0 = *reinterpret_cast<bf16x8*>(&w0);
    bf16x8 pb1 = *reinterpret_cast<bf16x8*>(&w1);
    // V^T as A-operand + PV (O^T = V^T * P)
    #pragma unroll
    for (int vcb = 0; vcb < 4; ++vcb) {
      bf16x8 vf0 = *reinterpret_cast<const bf16x8*>(vp + (size_t)vcb * 32 * T_SEQ + kv0);
      bf16x8 vf1 = *reinterpret_cast<const bf16x8*>(vp + (size_t)vcb * 32 * T_SEQ + kv0 + 16);
      acc[vcb] = __builtin_amdgcn_mfma_f32_32x32x16_bf16(vf0, pb0, acc[vcb], 0, 0, 0);
      acc[vcb] = __builtin_amdgcn_mfma_f32_32x32x16_bf16(vf1, pb1, acc[vcb], 0, 0, 0);
    }
  }
  // write partial: o^T[vc][q] bf16 + stats
  const size_t pbase = (size_t)wave_id * (HD * 32);
  #pragma unroll
  for (int vcb = 0; vcb < 4; ++vcb)
    #pragma unroll
    for (int r = 0; r < 16; ++r) {
      int vc = vcb * 32 + (r & 3) + 8 * (r >> 2) + 4 * lh;
      po[pbase + (size_t)vc * 32 + lq] = f2bf(acc[vcb][r]);
    }
  if (lane < 32) {
    pm[wave_id * 32 + lq] = mrun;
    pl[wave_id * 32 + lq] = lrun;
  }
}

// ---------------- Kernel 3: merge partials + diff + RMS + store -----------
template<int LOG2S>
__global__ __launch_bounds__(256) void diff_merge(
    const unsigned short* __restrict__ po, const float* __restrict__ pm,
    const float* __restrict__ pl,
    const float* __restrict__ lq1, const float* __restrict__ lq2,
    const float* __restrict__ lk1, const float* __restrict__ lk2,
    const float* __restrict__ lnw, float* __restrict__ out)
{
  constexpr int S = 1 << LOG2S;
  __shared__ float red[4][32];
  const int tid = threadIdx.x, lane = tid & 63, wid = tid >> 6;
  const int q = tid & 31, vg = tid >> 5;       // vc = vg*16 + i
  const int bq = blockIdx.x;                    // b*128 + qt
  const int b = bq >> 7, qt = bq & 127;

  float la = lq1[lane] * lk1[lane];
  float lb = lq2[lane] * lk2[lane];
  #pragma unroll
  for (int off = 32; off >= 1; off >>= 1) {
    la += __shfl_xor(la, off);
    lb += __shfl_xor(lb, off);
  }
  const float lam = __expf(la) - __expf(lb) + LAMBDA_INIT;

  const int p1 = (bq * 2 + 0) * S;
  const int p2 = (bq * 2 + 1) * S;
  float w1[S], w2[S];
  {
    float ms[S];
    #pragma unroll
    for (int s = 0; s < S; ++s) ms[s] = pm[(p1 + s) * 32 + q];
    float M = ms[0];
    #pragma unroll
    for (int s = 1; s < S; ++s) M = fmaxf(M, ms[s]);
    float L = 0.f;
    #pragma unroll
    for (int s = 0; s < S; ++s) { w1[s] = __expf(ms[s] - M); L += w1[s] * pl[(p1 + s) * 32 + q]; }
    float inv = 1.f / L;
    #pragma unroll
    for (int s = 0; s < S; ++s) w1[s] *= inv;
  }
  {
    float ms[S];
    #pragma unroll
    for (int s = 0; s < S; ++s) ms[s] = pm[(p2 + s) * 32 + q];
    float M = ms[0];
    #pragma unroll
    for (int s = 1; s < S; ++s) M = fmaxf(M, ms[s]);
    float L = 0.f;
    #pragma unroll
    for (int s = 0; s < S; ++s) { w2[s] = __expf(ms[s] - M); L += w2[s] * pl[(p2 + s) * 32 + q]; }
    float inv = lam / L;
    #pragma unroll
    for (int s = 0; s < S; ++s) w2[s] *= inv;
  }
  float d[16], ss = 0.f;
  #pragma unroll
  for (int i = 0; i < 16; ++i) {
    int vc = vg * 16 + i;
    float a1 = 0.f, a2 = 0.f;
    #pragma unroll
    for (int s = 0; s < S; ++s) {
      a1 += w1[s] * bf2f(po[(size_t)(p1 + s) * (HD * 32) + (size_t)vc * 32 + q]);
      a2 += w2[s] * bf2f(po[(size_t)(p2 + s) * (HD * 32) + (size_t)vc * 32 + q]);
    }
    d[i] = a1 - a2;
    ss += d[i] * d[i];
  }
  ss += __shfl_xor(ss, 32);
  if (lane < 32) red[wid][q] = ss;
  __syncthreads();
  float tot = red[0][q] + red[1][q] + red[2][q] + red[3][q];
  float rinv = 1.f / sqrtf(tot * (1.0f / HD) + 1e-5f);
  float* op = out + ((size_t)b * T_SEQ + qt * 32 + q) * HD + vg * 16;
  #pragma unroll
  for (int i = 0; i < 16; ++i) op[i] = OUT_SCALE * d[i] * rinv * lnw[vg * 16 + i];
}

extern "C" void kernel_launch(void* const* d_in, const int* in_sizes, int n_in,
                              void* d_out, int out_size, void* d_ws, size_t ws_size,
                              hipStream_t stream) {
  const float* x   = (const float*)d_in[0];
  const float* wq  = (const float*)d_in[1];
  const float* wk  = (const float*)d_in[2];
  const float* wv  = (const float*)d_in[3];
  const float* lq1 = (const float*)d_in[4];
  const float* lq2 = (const float*)d_in[5];
  const float* lk1 = (const float*)d_in[6];
  const float* lk2 = (const float*)d_in[7];
  const float* lnw = (const float*)d_in[8];
  float* out = (float*)d_out;

  const size_t N = (size_t)NB * T_SEQ * HD;     // 1,048,576
  int log2S = 2;
  for (; log2S > 0; --log2S) {
    size_t parts = (size_t)NB * 128 * 2 * (1u << log2S);
    size_t need = 3 * N * 2 + parts * (HD * 32) * 2 + parts * 32 * 4 * 2;
    if (need <= ws_size) break;
  }
  const size_t parts = (size_t)NB * 128 * 2 * (1u << log2S);

  unsigned short* qb = (unsigned short*)d_ws;
  unsigned short* kb = qb + N;
  unsigned short* vt = kb + N;
  unsigned short* po = vt + N;
  float* pm = (float*)(po + parts * (HD * 32));
  float* pl = pm + parts * 32;

  qkv_proj<<<dim3(128, 3), 256, 0, stream>>>(x, wq, wk, wv, qb, kb, vt);
  const int ablocks = (int)(parts / 4);
  switch (log2S) {
    case 2:
      diff_attn_part<2><<<dim3(ablocks), 256, 0, stream>>>(qb, kb, vt, po, pm, pl);
      diff_merge<2><<<dim3(NB * 128), 256, 0, stream>>>(po, pm, pl, lq1, lq2, lk1, lk2, lnw, out);
      break;
    case 1:
      diff_attn_part<1><<<dim3(ablocks), 256, 0, stream>>>(qb, kb, vt, po, pm, pl);
      diff_merge<1><<<dim3(NB * 128), 256, 0, stream>>>(po, pm, pl, lq1, lq2, lk1, lk2, lnw, out);
      break;
    default:
      diff_attn_part<0><<<dim3(ablocks), 256, 0, stream>>>(qb, kb, vt, po, pm, pl);
      diff_merge<0><<<dim3(NB * 128), 256, 0, stream>>>(po, pm, pl, lq1, lq2, lk1, lk2, lnw, out);
      break;
  }
}